// Round 9
// baseline (706.420 us; speedup 1.0000x reference)
//
#include <hip/hip_runtime.h>

// ShootingBlock: only the u-trajectory is observable (traj records y[2K:];
// du = relu(u)@theta^T + bias is self-contained; Mbar/Mbar_b are identity).
//
// R15 (post-mortem of R14, 525us): R14 validated counted-vmcnt+raw-barrier.
// Remaining cost: epilogue HBM round trips (u/acc/yw ~36MB/feval) that only
// exist because RK4 state crosses kernel boundaries. Fix: re-tile so fusion
// is block-LOCAL: each block owns 16 full rows (m) x all 512 features.
// Stage j+1's A-operand (rows m0..15, all e) is produced by the same block
// at stage j -> ONE kernel runs all 20 fevals, no grid sync, blocks fully
// independent.
//   * u + RK4 acc in registers (16+16 f32/thread). A = split3(relu(y)) in
//     LDS (48KB, rebuilt per stage; row pitch 516 ushorts = conflict-free
//     writes; fragment reads = R10-proven layout row=nl,k=qq*8).
//   * theta streamed with the R14-proven DMA discipline: 48KB phases
//     (256 n-rows x 32 k), double-buffered, quad-swizzle chunks verbatim,
//     per-phase {vmcnt(0) -> s_barrier -> prefetch next}.
//   * ya/yb/acc global arrays and init_kernel GONE. Per-feval global
//     traffic ~43MB -> ~0 (theta is L2-resident).
// Grid 256 blocks x 512 thr (8 waves, 2/SIMD, 1 block/CU @ 144.4KB LDS).
// Numerics: same 6 products, same k-order, same RK4 fmaf forms ->
// absmax must be bit-identical (4.835703e+24).

namespace {

constexpr int KP = 1024;
constexpr int D  = 512;
constexpr int M  = 4096;

typedef __attribute__((ext_vector_type(8))) short short8;   // 8 bf16 (4 VGPRs)
typedef __attribute__((ext_vector_type(4))) float f32x4;

__device__ __forceinline__ unsigned short f2bf(float f) {  // RNE
  unsigned int u = __float_as_uint(f);
  u += 0x7FFF + ((u >> 16) & 1);
  return (unsigned short)(u >> 16);
}
__device__ __forceinline__ float bf2f(unsigned short h) {
  return __uint_as_float(((unsigned int)h) << 16);
}

__device__ __forceinline__ void glds16(const unsigned short* g, unsigned short* l) {
  __builtin_amdgcn_global_load_lds(
      (__attribute__((address_space(1))) const void*)g,
      (__attribute__((address_space(3))) void*)l, 16, 0, 0);
}

// ---------------------------------------------------------------------------
// part[z][d][e] = sum_{k in chunk z} ps[k][d] * relu(xs[k][e])   (std layout)
// ---------------------------------------------------------------------------
constexpr int KSPLIT = 8;

__global__ __launch_bounds__(256) void theta_partial_kernel(
    const float* __restrict__ xs, const float* __restrict__ ps,
    float* __restrict__ part) {
  __shared__ float As[32][68];  // ps, d-block
  __shared__ float Bs[32][68];  // relu(xs), e-block
  const int d0 = blockIdx.x * 64;
  const int e0 = blockIdx.y * 64;
  const int kb = blockIdx.z * (KP / KSPLIT);
  const int t  = threadIdx.x;
  const int tx = t & 15, ty = t >> 4;
  float acc[4][4] = {};

  for (int k0 = kb; k0 < kb + KP / KSPLIT; k0 += 32) {
#pragma unroll
    for (int p = 0; p < 2; ++p) {
      const int idx = t + p * 256;
      const int c4  = idx & 15;
      const int row = idx >> 4;
      const float4 av = *(const float4*)(ps + (size_t)(k0 + row) * D + d0 + c4 * 4);
      *(float4*)&As[row][c4 * 4] = av;
      float4 bv = *(const float4*)(xs + (size_t)(k0 + row) * D + e0 + c4 * 4);
      bv.x = fmaxf(bv.x, 0.f); bv.y = fmaxf(bv.y, 0.f);
      bv.z = fmaxf(bv.z, 0.f); bv.w = fmaxf(bv.w, 0.f);
      *(float4*)&Bs[row][c4 * 4] = bv;
    }
    __syncthreads();
#pragma unroll
    for (int kk = 0; kk < 32; ++kk) {
      const float4 a4 = *(const float4*)&As[kk][ty * 4];
      const float4 b4 = *(const float4*)&Bs[kk][tx * 4];
      const float a[4] = {a4.x, a4.y, a4.z, a4.w};
      const float b[4] = {b4.x, b4.y, b4.z, b4.w};
#pragma unroll
      for (int i = 0; i < 4; ++i)
#pragma unroll
        for (int j = 0; j < 4; ++j)
          acc[i][j] = fmaf(a[i], b[j], acc[i][j]);
    }
    __syncthreads();
  }
  float* dst = part + (size_t)blockIdx.z * D * D;
#pragma unroll
  for (int i = 0; i < 4; ++i) {
    float4 v;
    v.x = acc[i][0]; v.y = acc[i][1]; v.z = acc[i][2]; v.w = acc[i][3];
    *(float4*)(dst + (size_t)(d0 + ty * 4 + i) * D + e0 + tx * 4) = v;
  }
}

// theta = -(sum partials); split-3 into bf16 arrays th0,th1,th2 [d][e]
__global__ __launch_bounds__(256) void theta_combine_kernel(
    const float* __restrict__ part, unsigned short* __restrict__ th0,
    unsigned short* __restrict__ th1, unsigned short* __restrict__ th2) {
  const size_t i = (size_t)blockIdx.x * 256 + threadIdx.x;  // float4 index
  float4 s = ((const float4*)part)[i];
#pragma unroll
  for (int z = 1; z < KSPLIT; ++z) {
    const float4 v = ((const float4*)(part + (size_t)z * D * D))[i];
    s.x += v.x; s.y += v.y; s.z += v.z; s.w += v.w;
  }
  const float vv[4] = {-s.x, -s.y, -s.z, -s.w};
  ushort4 h0, h1, h2;
  unsigned short* p0[4] = {&h0.x, &h0.y, &h0.z, &h0.w};
  unsigned short* p1[4] = {&h1.x, &h1.y, &h1.z, &h1.w};
  unsigned short* p2[4] = {&h2.x, &h2.y, &h2.z, &h2.w};
#pragma unroll
  for (int c = 0; c < 4; ++c) {
    const float v = vv[c];
    const unsigned short a0 = f2bf(v);
    const float r1 = v - bf2f(a0);
    const unsigned short a1 = f2bf(r1);
    const float r2 = r1 - bf2f(a1);
    *p0[c] = a0; *p1[c] = a1; *p2[c] = f2bf(r2);
  }
  ((ushort4*)th0)[i] = h0;
  ((ushort4*)th1)[i] = h1;
  ((ushort4*)th2)[i] = h2;
}

__global__ __launch_bounds__(256) void bias_kernel(const float* __restrict__ ps,
                                                   float* __restrict__ bias) {
  __shared__ float part[4][64];
  const int dc = threadIdx.x & 63;
  const int sl = threadIdx.x >> 6;
  const int d  = blockIdx.x * 64 + dc;
  float s = 0.f;
  for (int k = sl * 256; k < sl * 256 + 256; ++k) s += ps[(size_t)k * D + d];
  part[sl][dc] = s;
  __syncthreads();
  if (threadIdx.x < 64) {
    const int c = threadIdx.x;
    bias[blockIdx.x * 64 + c] =
        -(part[0][c] + part[1][c] + part[2][c] + part[3][c]);
  }
}

// ---------------------------------------------------------------------------
// Fused RK4: block = 16 m-rows x 512 n (all features). 512 thr = 8 waves;
// wave w owns n-slices [w*32, w*32+32) and [256+w*32, ...). Thread's 16
// outputs: (m = m0+qq*4+r, n = h*256 + w*32 + nf*16 + nl), h,nf in {0,1}.
// Per feval: 16 e-slabs x 2 n-half phases; theta phase = 48KB DMA
// (double-buffered, buf = h), A resident in LDS (48KB, rebuilt per stage).
// ---------------------------------------------------------------------------
__global__ __launch_bounds__(512, 1) void fused_rk4_kernel(
    const float* __restrict__ inp, const unsigned short* __restrict__ th0,
    const unsigned short* __restrict__ th1, const unsigned short* __restrict__ th2,
    const float* __restrict__ bias, const float* __restrict__ bt,
    float* __restrict__ out) {
  __shared__ unsigned short A_lds[3 * 16 * 516];   // 49,536 B (516 pitch)
  __shared__ unsigned short T_lds[2][3][256][32];  // 98,304 B theta dbuf
  const int t    = threadIdx.x;
  const int w    = t >> 6;         // wave 0..7
  const int lane = t & 63;
  const int nl   = lane & 15;
  const int qq   = lane >> 4;
  const int m0   = blockIdx.x * 16;
  const unsigned short* Tarr[3] = {th0, th1, th2};

  float u[2][2][4], ra[2][2][4], bb[2][2];
#pragma unroll
  for (int h = 0; h < 2; ++h)
#pragma unroll
    for (int nf = 0; nf < 2; ++nf) {
      const int n = h * 256 + w * 32 + nf * 16 + nl;
      bb[h][nf] = bias[n];
#pragma unroll
      for (int r = 0; r < 4; ++r) {
        const size_t off = (size_t)(m0 + qq * 4 + r) * D + n;
        const float v = inp[off];
        u[h][nf][r] = v;
        ra[h][nf][r] = 0.f;
        out[off] = v;                       // out[0] = inp
      }
    }

  // Build A = split3(relu(v)) into LDS. Writes: bank = (8qq + nl/2) + c,
  // 32 distinct banks, 2B pairs merge in-dword -> conflict-free.
  auto buildA = [&](const float (&v)[2][2][4]) {
#pragma unroll
    for (int h = 0; h < 2; ++h)
#pragma unroll
      for (int nf = 0; nf < 2; ++nf)
#pragma unroll
        for (int r = 0; r < 4; ++r) {
          const float ry = fmaxf(v[h][nf][r], 0.f);
          const unsigned short a0 = f2bf(ry);
          const float r1 = ry - bf2f(a0);
          const unsigned short a1 = f2bf(r1);
          const unsigned short a2 = f2bf(r1 - bf2f(a1));
          const int idx = (qq * 4 + r) * 516 + h * 256 + w * 32 + nf * 16 + nl;
          A_lds[idx]         = a0;
          A_lds[8256 + idx]  = a1;
          A_lds[16512 + idx] = a2;
        }
  };

  // Theta phase DMA: 48KB = 3072 16B-chunks; chunk c = (w*6+j)*64 + lane.
  // Decompose: split s = c>>10 (wave-uniform; 64-blocks never straddle),
  // row rr = (c&1023)>>2, slot qs = c&3 holds global quad q = qs^(rr&3)
  // (R6/R14-proven quad swizzle). LDS dest = base + c*16B (HW adds lane*16).
  auto dmaT = [&](int buf, int es, int h) {
    const int e0 = es * 32;
    const int hb = h * 256;
#pragma unroll
    for (int j = 0; j < 6; ++j) {
      const int cb  = (w * 6 + j) * 64;     // wave-uniform chunk base
      const int s   = cb >> 10;             // wave-uniform split
      const int rem = (cb & 1023) + lane;   // < 1024
      const int rr  = rem >> 2;
      const int q   = (rem & 3) ^ (rr & 3);
      unsigned short* dst = &T_lds[buf][0][0][0] + (size_t)cb * 8;
      glds16(Tarr[s] + (size_t)(hb + rr) * D + e0 + q * 8, dst);
    }
  };

  buildA(u);
  __syncthreads();
  dmaT(0, 0, 0);   // prologue: phase (0, h=0)

  for (int g = 0; g < 20; ++g) {
    f32x4 C[2][2];
#pragma unroll
    for (int h = 0; h < 2; ++h)
#pragma unroll
      for (int nf = 0; nf < 2; ++nf) C[h][nf] = (f32x4){0.f, 0.f, 0.f, 0.f};

    for (int es = 0; es < 16; ++es) {
      const int e0 = es * 32;

      // ---------- phase h = 0 (theta buf 0) ----------
      asm volatile("s_waitcnt vmcnt(0)" ::: "memory");
      __builtin_amdgcn_sched_barrier(0);
      __builtin_amdgcn_s_barrier();
      __builtin_amdgcn_sched_barrier(0);
      dmaT(1, es, 1);                       // prefetch (es, h=1)

      short8 av[3];
#pragma unroll
      for (int s = 0; s < 3; ++s)
        av[s] = *(const short8*)&A_lds[s * 8256 + nl * 516 + e0 + qq * 8];
      {
        short8 bv[2][3];
#pragma unroll
        for (int nf = 0; nf < 2; ++nf) {
          const int rr  = w * 32 + nf * 16 + nl;
          const int pos = (qq ^ (rr & 3)) * 8;
#pragma unroll
          for (int s = 0; s < 3; ++s)
            bv[nf][s] = *(const short8*)&T_lds[0][s][rr][pos];
        }
#pragma unroll
        for (int nf = 0; nf < 2; ++nf) {
          f32x4 c = C[0][nf];
          c = __builtin_amdgcn_mfma_f32_16x16x32_bf16(av[0], bv[nf][0], c, 0, 0, 0);
          c = __builtin_amdgcn_mfma_f32_16x16x32_bf16(av[0], bv[nf][1], c, 0, 0, 0);
          c = __builtin_amdgcn_mfma_f32_16x16x32_bf16(av[1], bv[nf][0], c, 0, 0, 0);
          c = __builtin_amdgcn_mfma_f32_16x16x32_bf16(av[0], bv[nf][2], c, 0, 0, 0);
          c = __builtin_amdgcn_mfma_f32_16x16x32_bf16(av[1], bv[nf][1], c, 0, 0, 0);
          c = __builtin_amdgcn_mfma_f32_16x16x32_bf16(av[2], bv[nf][0], c, 0, 0, 0);
          C[0][nf] = c;
        }
      }

      // ---------- phase h = 1 (theta buf 1) ----------
      asm volatile("s_waitcnt vmcnt(0)" ::: "memory");
      __builtin_amdgcn_sched_barrier(0);
      __builtin_amdgcn_s_barrier();
      __builtin_amdgcn_sched_barrier(0);
      if (!(g == 19 && es == 15)) dmaT(0, (es + 1) & 15, 0);  // next (es+1,0)
      {
        short8 bv[2][3];
#pragma unroll
        for (int nf = 0; nf < 2; ++nf) {
          const int rr  = w * 32 + nf * 16 + nl;
          const int pos = (qq ^ (rr & 3)) * 8;
#pragma unroll
          for (int s = 0; s < 3; ++s)
            bv[nf][s] = *(const short8*)&T_lds[1][s][rr][pos];
        }
#pragma unroll
        for (int nf = 0; nf < 2; ++nf) {
          f32x4 c = C[1][nf];
          c = __builtin_amdgcn_mfma_f32_16x16x32_bf16(av[0], bv[nf][0], c, 0, 0, 0);
          c = __builtin_amdgcn_mfma_f32_16x16x32_bf16(av[0], bv[nf][1], c, 0, 0, 0);
          c = __builtin_amdgcn_mfma_f32_16x16x32_bf16(av[1], bv[nf][0], c, 0, 0, 0);
          c = __builtin_amdgcn_mfma_f32_16x16x32_bf16(av[0], bv[nf][2], c, 0, 0, 0);
          c = __builtin_amdgcn_mfma_f32_16x16x32_bf16(av[1], bv[nf][1], c, 0, 0, 0);
          c = __builtin_amdgcn_mfma_f32_16x16x32_bf16(av[2], bv[nf][0], c, 0, 0, 0);
          C[1][nf] = c;
        }
      }
    }

    // ---- feval epilogue: RK4 state entirely in registers ------------------
    // A-rebuild race audit: A last read at phase (15,0); all waves passed
    // barrier (15,1) before any wave reaches here; phase (15,1) touches only
    // T_lds[1]. __syncthreads below publishes A before next feval's reads.
    const int st = g >> 2;
    const float dt = bt[st + 1] - bt[st];
    const int md = g & 3;
    const float cn = (md == 2) ? dt : 0.5f * dt;
    const float s6 = dt * (1.f / 6.f);
    float y[2][2][4];
#pragma unroll
    for (int h = 0; h < 2; ++h)
#pragma unroll
      for (int nf = 0; nf < 2; ++nf)
#pragma unroll
        for (int r = 0; r < 4; ++r) {
          const float kv = C[h][nf][r] + bb[h][nf];
          if (md == 0) {
            ra[h][nf][r] = kv;
            y[h][nf][r] = fmaf(cn, kv, u[h][nf][r]);
          } else if (md <= 2) {
            ra[h][nf][r] = fmaf(2.f, kv, ra[h][nf][r]);
            y[h][nf][r] = fmaf(cn, kv, u[h][nf][r]);
          } else {
            const float yy = fmaf(s6, ra[h][nf][r] + kv, u[h][nf][r]);
            y[h][nf][r] = yy;
            u[h][nf][r] = yy;
            out[(size_t)(st + 1) * M * D +
                (size_t)(m0 + qq * 4 + r) * D + h * 256 + w * 32 + nf * 16 + nl] = yy;
          }
        }
    if (g < 19) {
      buildA(y);
      __syncthreads();
    }
  }
}

}  // namespace

extern "C" void kernel_launch(void* const* d_in, const int* in_sizes, int n_in,
                              void* d_out, int out_size, void* d_ws, size_t ws_size,
                              hipStream_t stream) {
  (void)in_sizes; (void)n_in; (void)out_size; (void)ws_size;
  const float* xs  = (const float*)d_in[0];  // x_params (K,1,D)
  const float* ps  = (const float*)d_in[1];  // p_params (K,1,D)
  // d_in[2] Mbar, d_in[3] Mbar_b: identity -> inv() no-op
  const float* inp = (const float*)d_in[4];  // (M,1,D)
  const float* bt  = (const float*)d_in[5];  // (T,)
  float* out = (float*)d_out;                // (T, M, 1, D)
  float* ws  = (float*)d_ws;

  float* part = ws;                           // KSPLIT*D*D floats (8 MB)
  float* bias = part + (size_t)M * D;         // 512
  unsigned short* th0 = (unsigned short*)(bias + 512);   // D*D bf16 each
  unsigned short* th1 = th0 + (size_t)D * D;
  unsigned short* th2 = th1 + (size_t)D * D;

  theta_partial_kernel<<<dim3(8, 8, KSPLIT), 256, 0, stream>>>(xs, ps, part);
  theta_combine_kernel<<<(D * D) / (4 * 256), 256, 0, stream>>>(part, th0, th1, th2);
  bias_kernel<<<D / 64, 256, 0, stream>>>(ps, bias);

  fused_rk4_kernel<<<M / 16, 512, 0, stream>>>(inp, th0, th1, th2, bias, bt, out);
}